// Round 24
// baseline (79.570 us; speedup 1.0000x reference)
//
#include <hip/hip_runtime.h>
#include <hip/hip_bf16.h>

typedef __bf16 bf16x8 __attribute__((ext_vector_type(8)));
typedef float f32x4 __attribute__((ext_vector_type(4)));
typedef unsigned short u16x8 __attribute__((ext_vector_type(8)));

#define NB 8
#define NT 2048
#define NC 1024
#define NH 64

__device__ __forceinline__ unsigned short bfbits(float f) {
    return __builtin_bit_cast(unsigned short, (__bf16)f);
}

__device__ __forceinline__ void gl_lds16(const void* g, void* l) {
    __builtin_amdgcn_global_load_lds(
        (const __attribute__((address_space(1))) void*)g,
        (__attribute__((address_space(3))) void*)l, 16, 0, 0);
}
__device__ __forceinline__ void gl_lds16_nt(const void* g, void* l) {
    __builtin_amdgcn_global_load_lds(
        (const __attribute__((address_space(1))) void*)g,
        (__attribute__((address_space(3))) void*)l, 16, 0, 2);   // aux=2: NT
}

// ---------------- kernel 1: W -> W^T (bf16) ----------------
__global__ __launch_bounds__(256) void wt_kernel(const float* __restrict__ Wq,
                                                 const float* __restrict__ Wk,
                                                 const float* __restrict__ Wv,
                                                 unsigned short* __restrict__ Wt) {
    int idx = blockIdx.x * 256 + threadIdx.x;
    int n = idx >> 16;
    int r = idx & 65535;
    int c = r >> 6;
    int h = r & 63;
    const float* W = (n == 0) ? Wq : ((n == 1) ? Wk : Wv);
    float x = W[c * 64 + h];
    Wt[(n << 16) + h * 1024 + c] = bfbits(x);
}

// ---------------- kernel 2: pipelined gl_lds QKV projection + NT on X (R20, keep) ----------------
__global__ __launch_bounds__(256, 3) void proj_kernel(const float* __restrict__ Xv,
                                                      const float* __restrict__ Xk,
                                                      const float* __restrict__ Xq,
                                                      const unsigned short* __restrict__ Wt,
                                                      unsigned short* __restrict__ Q,
                                                      unsigned short* __restrict__ K,
                                                      unsigned short* __restrict__ VT) {
    __shared__ __align__(16) char Xs[2][16384];
    __shared__ __align__(16) char Ws[2][8192];

    int type = blockIdx.x >> 8;          // 0=Q,1=K,2=V
    int mt   = blockIdx.x & 255;
    int row0 = mt << 6;
    int phase = mt & 15;                 // k-chunk rotation (stagger)
    const float* X = (type == 0) ? Xq : ((type == 1) ? Xk : Xv);

    int tid  = threadIdx.x;
    int w    = tid >> 6;
    int lane = tid & 63;
    int lo = lane & 15, hi = lane >> 4;
    int swz = (lo & 7) << 4;

    const char* Xbase = (const char*)X + (size_t)row0 * 4096;
    const char* Wbase = (const char*)(Wt + (type << 16));

    int xr_l = lane >> 4;
    int xc_l = (lane & 15) * 16;
    int wr_l = lane >> 3;
    int wc_l = (lane & 7) * 16;

    f32x4 acc[4];
#pragma unroll
    for (int ct = 0; ct < 4; ++ct) acc[ct] = 0.f;

    auto stage = [&](int kc, int buf) {
#pragma unroll
        for (int i = 0; i < 4; ++i) {
            int g = w * 4 + i;
            int r = g * 4 + xr_l;
            gl_lds16_nt(Xbase + (size_t)r * 4096 + kc * 256 + (xc_l ^ ((r & 7) << 4)),
                        Xs[buf] + g * 1024);
        }
#pragma unroll
        for (int i = 0; i < 2; ++i) {
            int g = w * 2 + i;
            int h = g * 8 + wr_l;
            gl_lds16(Wbase + (size_t)h * 2048 + kc * 128 + (wc_l ^ ((h & 7) << 4)),
                     Ws[buf] + g * 1024);
        }
    };

    auto compute = [&](int buf) {
        const char* xrow = Xs[buf] + (w * 16 + lo) * 256;
        const char* wb   = Ws[buf];
#pragma unroll
        for (int ks = 0; ks < 2; ++ks) {
            f32x4 a0 = *(const f32x4*)(xrow + ((ks * 128 + hi * 32) ^ swz));
            f32x4 a1 = *(const f32x4*)(xrow + ((ks * 128 + hi * 32 + 16) ^ swz));
            bf16x8 af;
            af[0] = (__bf16)a0[0]; af[1] = (__bf16)a0[1]; af[2] = (__bf16)a0[2]; af[3] = (__bf16)a0[3];
            af[4] = (__bf16)a1[0]; af[5] = (__bf16)a1[1]; af[6] = (__bf16)a1[2]; af[7] = (__bf16)a1[3];
#pragma unroll
            for (int ct = 0; ct < 4; ++ct) {
                bf16x8 bf = *(const bf16x8*)(wb + (ct * 16 + lo) * 128 + ((ks * 64 + hi * 16) ^ swz));
                acc[ct] = __builtin_amdgcn_mfma_f32_16x16x32_bf16(af, bf, acc[ct], 0, 0, 0);
            }
        }
    };

    stage(phase, 0);
    stage((1 + phase) & 15, 1);

    for (int c = 0; c < 16; ++c) {
        int buf = c & 1;
        if (c < 15) asm volatile("s_waitcnt vmcnt(6)" ::: "memory");
        else        asm volatile("s_waitcnt vmcnt(0)" ::: "memory");
        __builtin_amdgcn_s_barrier();
        compute(buf);
        if (c + 2 < 16) {
            __builtin_amdgcn_s_barrier();
            stage((c + 2 + phase) & 15, buf);
        }
    }

    if (type < 2) {
        unsigned short* O = (type == 0) ? Q : K;
#pragma unroll
        for (int ct = 0; ct < 4; ++ct)
#pragma unroll
            for (int r = 0; r < 4; ++r) {
                int row = row0 + w * 16 + hi * 4 + r;
                int h = lo + 16 * ct;
                O[(size_t)row * NH + h] = bfbits(acc[ct][r]);
            }
    } else {
        int trow = row0 + w * 16 + hi * 4;
        int b = trow >> 11;
        int t = trow & 2047;
#pragma unroll
        for (int ct = 0; ct < 4; ++ct) {
            int h = lo + 16 * ct;
            ushort4 pk;
            pk.x = bfbits(acc[ct][0]);
            pk.y = bfbits(acc[ct][1]);
            pk.z = bfbits(acc[ct][2]);
            pk.w = bfbits(acc[ct][3]);
            *(ushort4*)(VT + (size_t)(b * NH + h) * NT + t) = pk;
        }
    }
}

// ---------------- kernel 3: causal flash attention ----------------
// R21 body (64-wide chunks, fixed-shift softmax, swizzled P-LDS, K-prefetch).
// Occupancy 1.5x: grid 1024 (one q-tile/block, heavy-first) + launch_bounds(256,3)
// (~168-VGPR cap: enough for the ~160-reg live set, 3 blocks/CU). XCD pinning.
__global__ __launch_bounds__(256, 3) void attn_kernel(const unsigned short* __restrict__ Q,
                                                      const unsigned short* __restrict__ K,
                                                      const unsigned short* __restrict__ VT,
                                                      float* __restrict__ out) {
    __shared__ __align__(16) unsigned short p_lds[4 * 1024];
    __shared__ __align__(16) float acc_lds[4 * 16 * 64];
    __shared__ float l_lds[4][16];

    int b  = blockIdx.x & 7;              // XCD-pinned batch
    int qt = 127 - (blockIdx.x >> 3);     // heaviest tiles dispatch first
    int q0 = qt << 4;
    int w    = threadIdx.x >> 6;
    int lane = threadIdx.x & 63;
    int lo = lane & 15, hi = lane >> 4;

    const float SC = 0.03125f * 1.44269504088896340736f;  // C^-0.5 * log2(e)
    const unsigned short* qb = Q + (size_t)(b * NT + q0 + lo) * NH + hi * 8;
    bf16x8 qr0 = *(const bf16x8*)(qb);
    bf16x8 qr1 = *(const bf16x8*)(qb + 32);
    bf16x8 qf0, qf1;
#pragma unroll
    for (int jj = 0; jj < 8; ++jj) {
        qf0[jj] = (__bf16)((float)qr0[jj] * SC);
        qf1[jj] = (__bf16)((float)qr1[jj] * SC);
    }

    int Ct = (q0 + 79) >> 6;              // 64-wide chunks covering s <= q0+15
    int c0 = (Ct * w) >> 2;
    int c1 = (Ct * (w + 1)) >> 2;

    float l[4];
    f32x4 acc[4];
#pragma unroll
    for (int r = 0; r < 4; ++r) l[r] = 0.f;
#pragma unroll
    for (int ct = 0; ct < 4; ++ct) acc[ct] = 0.f;

    unsigned short* pl = p_lds + w * 1024;
    char* plb = (char*)pl;

    bf16x8 kn[8];
    if (c0 < c1) {
        const unsigned short* kp = K + (size_t)(b * NT + (c0 << 6) + lo) * NH + hi * 8;
#pragma unroll
        for (int g = 0; g < 4; ++g) {
            kn[2 * g]     = *(const bf16x8*)(kp + g * 16 * NH);
            kn[2 * g + 1] = *(const bf16x8*)(kp + g * 16 * NH + 32);
        }
    }

    for (int c = c0; c < c1; ++c) {
        int s0 = c << 6;
        bf16x8 kk[8];
#pragma unroll
        for (int i = 0; i < 8; ++i) kk[i] = kn[i];
        const unsigned short* vb = VT + (size_t)(b * NH + lo) * NT + s0 + hi * 8;
        bf16x8 vA0 = *(const bf16x8*)(vb);
        bf16x8 vA1 = *(const bf16x8*)(vb + 16 * NT);
        bf16x8 vA2 = *(const bf16x8*)(vb + 32 * NT);
        bf16x8 vA3 = *(const bf16x8*)(vb + 48 * NT);
        bf16x8 vB0 = *(const bf16x8*)(vb + 32);
        bf16x8 vB1 = *(const bf16x8*)(vb + 16 * NT + 32);
        bf16x8 vB2 = *(const bf16x8*)(vb + 32 * NT + 32);
        bf16x8 vB3 = *(const bf16x8*)(vb + 48 * NT + 32);
        if (c + 1 < c1) {
            const unsigned short* kp2 = K + (size_t)(b * NT + ((c + 1) << 6) + lo) * NH + hi * 8;
#pragma unroll
            for (int g = 0; g < 4; ++g) {
                kn[2 * g]     = *(const bf16x8*)(kp2 + g * 16 * NH);
                kn[2 * g + 1] = *(const bf16x8*)(kp2 + g * 16 * NH + 32);
            }
        }

        f32x4 S[4];
#pragma unroll
        for (int t = 0; t < 4; ++t) {
            f32x4 s = 0.f;
            s = __builtin_amdgcn_mfma_f32_16x16x32_bf16(qf0, kk[2 * t], s, 0, 0, 0);
            s = __builtin_amdgcn_mfma_f32_16x16x32_bf16(qf1, kk[2 * t + 1], s, 0, 0, 0);
            S[t] = s;
        }

#pragma unroll
        for (int r = 0; r < 4; ++r) {
            int qi = q0 + hi * 4 + r;
            int ql = hi * 4 + r;
            int sw = (ql & 7) << 4;
            float psum = 0.f;
#pragma unroll
            for (int t = 0; t < 4; ++t) {
                int sk = s0 + t * 16 + lo;
                float p = (sk <= qi) ? exp2f(S[t][r] - 32.f) : 0.f;
                psum += p;
                int byte = ql * 128 + ((((t * 16 + lo) * 2)) ^ sw);
                *(unsigned short*)(plb + byte) = bfbits(p);
            }
            l[r] += psum;
        }

        int rsw = (lo & 7) << 4;
        bf16x8 pa0 = *(const bf16x8*)(plb + lo * 128 + ((hi * 16) ^ rsw));
        bf16x8 pa1 = *(const bf16x8*)(plb + lo * 128 + (((4 + hi) * 16) ^ rsw));
        acc[0] = __builtin_amdgcn_mfma_f32_16x16x32_bf16(pa0, vA0, acc[0], 0, 0, 0);
        acc[1] = __builtin_amdgcn_mfma_f32_16x16x32_bf16(pa0, vA1, acc[1], 0, 0, 0);
        acc[2] = __builtin_amdgcn_mfma_f32_16x16x32_bf16(pa0, vA2, acc[2], 0, 0, 0);
        acc[3] = __builtin_amdgcn_mfma_f32_16x16x32_bf16(pa0, vA3, acc[3], 0, 0, 0);
        acc[0] = __builtin_amdgcn_mfma_f32_16x16x32_bf16(pa1, vB0, acc[0], 0, 0, 0);
        acc[1] = __builtin_amdgcn_mfma_f32_16x16x32_bf16(pa1, vB1, acc[1], 0, 0, 0);
        acc[2] = __builtin_amdgcn_mfma_f32_16x16x32_bf16(pa1, vB2, acc[2], 0, 0, 0);
        acc[3] = __builtin_amdgcn_mfma_f32_16x16x32_bf16(pa1, vB3, acc[3], 0, 0, 0);
    }

#pragma unroll
    for (int d = 1; d < 16; d <<= 1)
#pragma unroll
        for (int r = 0; r < 4; ++r)
            l[r] += __shfl_xor(l[r], d, 16);

#pragma unroll
    for (int r = 0; r < 4; ++r) {
        int ql = hi * 4 + r;
#pragma unroll
        for (int ct = 0; ct < 4; ++ct)
            acc_lds[(w * 16 + ql) * 64 + lo + 16 * ct] = acc[ct][r];
    }
    if (lo == 0) {
#pragma unroll
        for (int r = 0; r < 4; ++r)
            l_lds[w][hi * 4 + r] = l[r];
    }
    __syncthreads();

    int q  = threadIdx.x >> 4;
    int h0 = (threadIdx.x & 15) << 2;
    float L = l_lds[0][q] + l_lds[1][q] + l_lds[2][q] + l_lds[3][q];
    float ox = 0.f, oy = 0.f, oz = 0.f, ow = 0.f;
#pragma unroll
    for (int ww = 0; ww < 4; ++ww) {
        const float* p = acc_lds + (ww * 16 + q) * 64 + h0;
        ox += p[0]; oy += p[1]; oz += p[2]; ow += p[3];
    }
    float inv = 1.0f / L;
    float4 res = make_float4(ox * inv, oy * inv, oz * inv, ow * inv);
    *(float4*)(out + (size_t)(b * NT + q0 + q) * NH + h0) = res;
}

extern "C" void kernel_launch(void* const* d_in, const int* in_sizes, int n_in,
                              void* d_out, int out_size, void* d_ws, size_t ws_size,
                              hipStream_t stream) {
    const float* values  = (const float*)d_in[0];
    const float* keys    = (const float*)d_in[1];
    const float* queries = (const float*)d_in[2];
    const float* Wk = (const float*)d_in[3];
    const float* Wq = (const float*)d_in[4];
    const float* Wv = (const float*)d_in[5];
    float* out = (float*)d_out;

    unsigned short* Wt = (unsigned short*)d_ws;        // 196608 ushorts
    unsigned short* Qb = Wt + 196608;                  // Q,K,VT: 3x1048576 ushorts
    unsigned short* Kb = Qb + 1048576;
    unsigned short* VT = Kb + 1048576;

    wt_kernel<<<768, 256, 0, stream>>>(Wq, Wk, Wv, Wt);
    proj_kernel<<<768, 256, 0, stream>>>(values, keys, queries, Wt, Qb, Kb, VT);
    attn_kernel<<<1024, 256, 0, stream>>>(Qb, Kb, VT, out);
}

// Round 25
// 76.296 us; speedup vs baseline: 1.0429x; 1.0429x over previous
//
#include <hip/hip_runtime.h>
#include <hip/hip_bf16.h>

typedef __bf16 bf16x8 __attribute__((ext_vector_type(8)));
typedef float f32x4 __attribute__((ext_vector_type(4)));
typedef unsigned short u16x8 __attribute__((ext_vector_type(8)));

#define NB 8
#define NT 2048
#define NC 1024
#define NH 64

__device__ __forceinline__ unsigned short bfbits(float f) {
    return __builtin_bit_cast(unsigned short, (__bf16)f);
}

__device__ __forceinline__ void gl_lds16(const void* g, void* l) {
    __builtin_amdgcn_global_load_lds(
        (const __attribute__((address_space(1))) void*)g,
        (__attribute__((address_space(3))) void*)l, 16, 0, 0);
}
__device__ __forceinline__ void gl_lds16_nt(const void* g, void* l) {
    __builtin_amdgcn_global_load_lds(
        (const __attribute__((address_space(1))) void*)g,
        (__attribute__((address_space(3))) void*)l, 16, 0, 2);   // aux=2: NT
}

// ---------------- kernel 1: W -> W^T (bf16) ----------------
__global__ __launch_bounds__(256) void wt_kernel(const float* __restrict__ Wq,
                                                 const float* __restrict__ Wk,
                                                 const float* __restrict__ Wv,
                                                 unsigned short* __restrict__ Wt) {
    int idx = blockIdx.x * 256 + threadIdx.x;
    int n = idx >> 16;
    int r = idx & 65535;
    int c = r >> 6;
    int h = r & 63;
    const float* W = (n == 0) ? Wq : ((n == 1) ? Wk : Wv);
    float x = W[c * 64 + h];
    Wt[(n << 16) + h * 1024 + c] = bfbits(x);
}

// ---------------- kernel 2: pipelined gl_lds QKV projection + NT on X (R20, keep) ----------------
__global__ __launch_bounds__(256, 3) void proj_kernel(const float* __restrict__ Xv,
                                                      const float* __restrict__ Xk,
                                                      const float* __restrict__ Xq,
                                                      const unsigned short* __restrict__ Wt,
                                                      unsigned short* __restrict__ Q,
                                                      unsigned short* __restrict__ K,
                                                      unsigned short* __restrict__ VT) {
    __shared__ __align__(16) char Xs[2][16384];
    __shared__ __align__(16) char Ws[2][8192];

    int type = blockIdx.x >> 8;          // 0=Q,1=K,2=V
    int mt   = blockIdx.x & 255;
    int row0 = mt << 6;
    int phase = mt & 15;                 // k-chunk rotation (stagger)
    const float* X = (type == 0) ? Xq : ((type == 1) ? Xk : Xv);

    int tid  = threadIdx.x;
    int w    = tid >> 6;
    int lane = tid & 63;
    int lo = lane & 15, hi = lane >> 4;
    int swz = (lo & 7) << 4;

    const char* Xbase = (const char*)X + (size_t)row0 * 4096;
    const char* Wbase = (const char*)(Wt + (type << 16));

    int xr_l = lane >> 4;
    int xc_l = (lane & 15) * 16;
    int wr_l = lane >> 3;
    int wc_l = (lane & 7) * 16;

    f32x4 acc[4];
#pragma unroll
    for (int ct = 0; ct < 4; ++ct) acc[ct] = 0.f;

    auto stage = [&](int kc, int buf) {
#pragma unroll
        for (int i = 0; i < 4; ++i) {
            int g = w * 4 + i;
            int r = g * 4 + xr_l;
            gl_lds16_nt(Xbase + (size_t)r * 4096 + kc * 256 + (xc_l ^ ((r & 7) << 4)),
                        Xs[buf] + g * 1024);
        }
#pragma unroll
        for (int i = 0; i < 2; ++i) {
            int g = w * 2 + i;
            int h = g * 8 + wr_l;
            gl_lds16(Wbase + (size_t)h * 2048 + kc * 128 + (wc_l ^ ((h & 7) << 4)),
                     Ws[buf] + g * 1024);
        }
    };

    auto compute = [&](int buf) {
        const char* xrow = Xs[buf] + (w * 16 + lo) * 256;
        const char* wb   = Ws[buf];
#pragma unroll
        for (int ks = 0; ks < 2; ++ks) {
            f32x4 a0 = *(const f32x4*)(xrow + ((ks * 128 + hi * 32) ^ swz));
            f32x4 a1 = *(const f32x4*)(xrow + ((ks * 128 + hi * 32 + 16) ^ swz));
            bf16x8 af;
            af[0] = (__bf16)a0[0]; af[1] = (__bf16)a0[1]; af[2] = (__bf16)a0[2]; af[3] = (__bf16)a0[3];
            af[4] = (__bf16)a1[0]; af[5] = (__bf16)a1[1]; af[6] = (__bf16)a1[2]; af[7] = (__bf16)a1[3];
#pragma unroll
            for (int ct = 0; ct < 4; ++ct) {
                bf16x8 bf = *(const bf16x8*)(wb + (ct * 16 + lo) * 128 + ((ks * 64 + hi * 16) ^ swz));
                acc[ct] = __builtin_amdgcn_mfma_f32_16x16x32_bf16(af, bf, acc[ct], 0, 0, 0);
            }
        }
    };

    stage(phase, 0);
    stage((1 + phase) & 15, 1);

    for (int c = 0; c < 16; ++c) {
        int buf = c & 1;
        if (c < 15) asm volatile("s_waitcnt vmcnt(6)" ::: "memory");
        else        asm volatile("s_waitcnt vmcnt(0)" ::: "memory");
        __builtin_amdgcn_s_barrier();
        compute(buf);
        if (c + 2 < 16) {
            __builtin_amdgcn_s_barrier();
            stage((c + 2 + phase) & 15, buf);
        }
    }

    if (type < 2) {
        unsigned short* O = (type == 0) ? Q : K;
#pragma unroll
        for (int ct = 0; ct < 4; ++ct)
#pragma unroll
            for (int r = 0; r < 4; ++r) {
                int row = row0 + w * 16 + hi * 4 + r;
                int h = lo + 16 * ct;
                O[(size_t)row * NH + h] = bfbits(acc[ct][r]);
            }
    } else {
        int trow = row0 + w * 16 + hi * 4;
        int b = trow >> 11;
        int t = trow & 2047;
#pragma unroll
        for (int ct = 0; ct < 4; ++ct) {
            int h = lo + 16 * ct;
            ushort4 pk;
            pk.x = bfbits(acc[ct][0]);
            pk.y = bfbits(acc[ct][1]);
            pk.z = bfbits(acc[ct][2]);
            pk.w = bfbits(acc[ct][3]);
            *(ushort4*)(VT + (size_t)(b * NH + h) * NT + t) = pk;
        }
    }
}

// ---------------- kernel 3: causal flash attention (R21 config — best known) ----------------
// 64-wide chunks + fixed-shift softmax + swizzled P-LDS; launch_bounds(256,2)
// (keeps ~160-VGPR live set intact); complementary-pair balancing; XCD pinning.
__global__ __launch_bounds__(256, 2) void attn_kernel(const unsigned short* __restrict__ Q,
                                                      const unsigned short* __restrict__ K,
                                                      const unsigned short* __restrict__ VT,
                                                      float* __restrict__ out) {
    __shared__ __align__(16) unsigned short p_lds[4 * 1024];
    __shared__ __align__(16) float acc_lds[4 * 16 * 64];
    __shared__ float l_lds[4][16];

    int b = blockIdx.x & 7;               // XCD-pinned batch
    int j = blockIdx.x >> 3;              // 0..63 pair index
    int w    = threadIdx.x >> 6;
    int lane = threadIdx.x & 63;
    int lo = lane & 15, hi = lane >> 4;

    const float SC = 0.03125f * 1.44269504088896340736f;  // C^-0.5 * log2(e)
    unsigned short* pl = p_lds + w * 1024;
    char* plb = (char*)pl;

    for (int t2 = 0; t2 < 2; ++t2) {
        int qt = t2 ? (127 - j) : j;
        int q0 = qt << 4;

        const unsigned short* qb = Q + (size_t)(b * NT + q0 + lo) * NH + hi * 8;
        bf16x8 qr0 = *(const bf16x8*)(qb);
        bf16x8 qr1 = *(const bf16x8*)(qb + 32);
        bf16x8 qf0, qf1;
#pragma unroll
        for (int jj = 0; jj < 8; ++jj) {
            qf0[jj] = (__bf16)((float)qr0[jj] * SC);
            qf1[jj] = (__bf16)((float)qr1[jj] * SC);
        }

        int Ct = (q0 + 79) >> 6;          // 64-wide chunks covering s <= q0+15
        int c0 = (Ct * w) >> 2;
        int c1 = (Ct * (w + 1)) >> 2;

        float l[4];
        f32x4 acc[4];
#pragma unroll
        for (int r = 0; r < 4; ++r) l[r] = 0.f;
#pragma unroll
        for (int ct = 0; ct < 4; ++ct) acc[ct] = 0.f;

        bf16x8 kn[8];
        if (c0 < c1) {
            const unsigned short* kp = K + (size_t)(b * NT + (c0 << 6) + lo) * NH + hi * 8;
#pragma unroll
            for (int g = 0; g < 4; ++g) {
                kn[2 * g]     = *(const bf16x8*)(kp + g * 16 * NH);
                kn[2 * g + 1] = *(const bf16x8*)(kp + g * 16 * NH + 32);
            }
        }

        for (int c = c0; c < c1; ++c) {
            int s0 = c << 6;
            bf16x8 kk[8];
#pragma unroll
            for (int i = 0; i < 8; ++i) kk[i] = kn[i];
            const unsigned short* vb = VT + (size_t)(b * NH + lo) * NT + s0 + hi * 8;
            bf16x8 vA0 = *(const bf16x8*)(vb);
            bf16x8 vA1 = *(const bf16x8*)(vb + 16 * NT);
            bf16x8 vA2 = *(const bf16x8*)(vb + 32 * NT);
            bf16x8 vA3 = *(const bf16x8*)(vb + 48 * NT);
            bf16x8 vB0 = *(const bf16x8*)(vb + 32);
            bf16x8 vB1 = *(const bf16x8*)(vb + 16 * NT + 32);
            bf16x8 vB2 = *(const bf16x8*)(vb + 32 * NT + 32);
            bf16x8 vB3 = *(const bf16x8*)(vb + 48 * NT + 32);
            if (c + 1 < c1) {
                const unsigned short* kp2 = K + (size_t)(b * NT + ((c + 1) << 6) + lo) * NH + hi * 8;
#pragma unroll
                for (int g = 0; g < 4; ++g) {
                    kn[2 * g]     = *(const bf16x8*)(kp2 + g * 16 * NH);
                    kn[2 * g + 1] = *(const bf16x8*)(kp2 + g * 16 * NH + 32);
                }
            }

            f32x4 S[4];
#pragma unroll
            for (int t = 0; t < 4; ++t) {
                f32x4 s = 0.f;
                s = __builtin_amdgcn_mfma_f32_16x16x32_bf16(qf0, kk[2 * t], s, 0, 0, 0);
                s = __builtin_amdgcn_mfma_f32_16x16x32_bf16(qf1, kk[2 * t + 1], s, 0, 0, 0);
                S[t] = s;
            }

#pragma unroll
            for (int r = 0; r < 4; ++r) {
                int qi = q0 + hi * 4 + r;
                int ql = hi * 4 + r;
                int sw = (ql & 7) << 4;
                float psum = 0.f;
#pragma unroll
                for (int t = 0; t < 4; ++t) {
                    int sk = s0 + t * 16 + lo;
                    float p = (sk <= qi) ? exp2f(S[t][r] - 32.f) : 0.f;
                    psum += p;
                    int byte = ql * 128 + ((((t * 16 + lo) * 2)) ^ sw);
                    *(unsigned short*)(plb + byte) = bfbits(p);
                }
                l[r] += psum;
            }

            int rsw = (lo & 7) << 4;
            bf16x8 pa0 = *(const bf16x8*)(plb + lo * 128 + ((hi * 16) ^ rsw));
            bf16x8 pa1 = *(const bf16x8*)(plb + lo * 128 + (((4 + hi) * 16) ^ rsw));
            acc[0] = __builtin_amdgcn_mfma_f32_16x16x32_bf16(pa0, vA0, acc[0], 0, 0, 0);
            acc[1] = __builtin_amdgcn_mfma_f32_16x16x32_bf16(pa0, vA1, acc[1], 0, 0, 0);
            acc[2] = __builtin_amdgcn_mfma_f32_16x16x32_bf16(pa0, vA2, acc[2], 0, 0, 0);
            acc[3] = __builtin_amdgcn_mfma_f32_16x16x32_bf16(pa0, vA3, acc[3], 0, 0, 0);
            acc[0] = __builtin_amdgcn_mfma_f32_16x16x32_bf16(pa1, vB0, acc[0], 0, 0, 0);
            acc[1] = __builtin_amdgcn_mfma_f32_16x16x32_bf16(pa1, vB1, acc[1], 0, 0, 0);
            acc[2] = __builtin_amdgcn_mfma_f32_16x16x32_bf16(pa1, vB2, acc[2], 0, 0, 0);
            acc[3] = __builtin_amdgcn_mfma_f32_16x16x32_bf16(pa1, vB3, acc[3], 0, 0, 0);
        }

        // one-time 16-lane reduction of l
#pragma unroll
        for (int d = 1; d < 16; d <<= 1)
#pragma unroll
            for (int r = 0; r < 4; ++r)
                l[r] += __shfl_xor(l[r], d, 16);

        // dump per-wave partial state
#pragma unroll
        for (int r = 0; r < 4; ++r) {
            int ql = hi * 4 + r;
#pragma unroll
            for (int ct = 0; ct < 4; ++ct)
                acc_lds[(w * 16 + ql) * 64 + lo + 16 * ct] = acc[ct][r];
        }
        if (lo == 0) {
#pragma unroll
            for (int r = 0; r < 4; ++r)
                l_lds[w][hi * 4 + r] = l[r];
        }
        __syncthreads();

        // merge 4 s-splits: plain sums (shift identical across waves)
        int q  = threadIdx.x >> 4;
        int h0 = (threadIdx.x & 15) << 2;
        float L = l_lds[0][q] + l_lds[1][q] + l_lds[2][q] + l_lds[3][q];
        float ox = 0.f, oy = 0.f, oz = 0.f, ow = 0.f;
#pragma unroll
        for (int ww = 0; ww < 4; ++ww) {
            const float* p = acc_lds + (ww * 16 + q) * 64 + h0;
            ox += p[0]; oy += p[1]; oz += p[2]; ow += p[3];
        }
        float inv = 1.0f / L;
        float4 res = make_float4(ox * inv, oy * inv, oz * inv, ow * inv);
        *(float4*)(out + (size_t)(b * NT + q0 + q) * NH + h0) = res;
        __syncthreads();   // LDS reused by next tile
    }
}

extern "C" void kernel_launch(void* const* d_in, const int* in_sizes, int n_in,
                              void* d_out, int out_size, void* d_ws, size_t ws_size,
                              hipStream_t stream) {
    const float* values  = (const float*)d_in[0];
    const float* keys    = (const float*)d_in[1];
    const float* queries = (const float*)d_in[2];
    const float* Wk = (const float*)d_in[3];
    const float* Wq = (const float*)d_in[4];
    const float* Wv = (const float*)d_in[5];
    float* out = (float*)d_out;

    unsigned short* Wt = (unsigned short*)d_ws;        // 196608 ushorts
    unsigned short* Qb = Wt + 196608;                  // Q,K,VT: 3x1048576 ushorts
    unsigned short* Kb = Qb + 1048576;
    unsigned short* VT = Kb + 1048576;

    wt_kernel<<<768, 256, 0, stream>>>(Wq, Wk, Wv, Wt);
    proj_kernel<<<768, 256, 0, stream>>>(values, keys, queries, Wt, Qb, Kb, VT);
    attn_kernel<<<512, 256, 0, stream>>>(Qb, Kb, VT, out);
}